// Round 1
// baseline (412.555 us; speedup 1.0000x reference)
//
#include <hip/hip_runtime.h>

#define T 4096
#define B 64
#define D 256

// Kernel A: per-batch doc search + gather + linear0 (x = g @ W0^T + b0), gate.
// 64 blocks x 256 threads. Tiny (reads ~1MB exe + 64KB W0-per-block from L2).
__global__ __launch_bounds__(256) void prep_kernel(
    const int* __restrict__ batch_nodes, const int* __restrict__ exe,
    const float* __restrict__ graph_dict, const float* __restrict__ W0,
    const float* __restrict__ b0, float* __restrict__ x_ws,
    float* __restrict__ gate_out)
{
    const int b   = blockIdx.x;
    const int tid = threadIdx.x;

    // last t with exe[b,t]==1 (thread-strided; t ascending so overwrite = max)
    int best = -1;
    const int* erow = exe + (size_t)b * T;
    for (int t = tid; t < T; t += 256)
        if (erow[t] == 1) best = t;

    // wave max (width 64), then cross-wave via LDS
    for (int off = 32; off > 0; off >>= 1) {
        int o = __shfl_down(best, off, 64);
        best = best > o ? best : o;
    }
    __shared__ int sred[4];
    __shared__ int s_doc;
    const int wid = tid >> 6, lane = tid & 63;
    if (lane == 0) sred[wid] = best;
    __syncthreads();
    if (tid == 0) {
        int m = sred[0];
        if (sred[1] > m) m = sred[1];
        if (sred[2] > m) m = sred[2];
        if (sred[3] > m) m = sred[3];
        s_doc = m;
    }
    __syncthreads();

    const int  doc  = s_doc;
    const bool has  = doc >= 0;
    const int  safe = has ? doc : 0;
    const int  node = batch_nodes[(size_t)b * T + safe];

    __shared__ float s_g[D];
    s_g[tid] = has ? graph_dict[(size_t)node * D + tid] : 0.0f;
    __syncthreads();

    // x[b,e] = b0[e] + sum_d g[d] * W0[e,d]   (when !has: x = b0 — bias stays!)
    const int e = tid;
    const float4* wrow = (const float4*)(W0 + (size_t)e * D);
    float acc = b0[e];
    #pragma unroll 8
    for (int d4 = 0; d4 < D / 4; ++d4) {
        float4 w = wrow[d4];
        acc += s_g[d4 * 4 + 0] * w.x + s_g[d4 * 4 + 1] * w.y
             + s_g[d4 * 4 + 2] * w.z + s_g[d4 * 4 + 3] * w.w;
    }
    x_ws[(size_t)b * D + e] = acc;
    if (tid == 0) gate_out[b] = has ? 1.0f : 0.0f;
}

// Kernel B: one wave per (b,t). Lane i loads float4 src[t,b,4i..4i+3]
// (64 lanes * 16B = 1KB contiguous, fully coalesced), dots with x[b],
// wave shuffle-reduce, lane 0 writes sim[b,t] * 1/16.
// All 4 waves of a block share b -> x fragment hits L1/broadcasts.
__global__ __launch_bounds__(256) void sim_kernel(
    const float* __restrict__ src, const float* __restrict__ x_ws,
    float* __restrict__ out)
{
    const int wave = (blockIdx.x << 2) | (threadIdx.x >> 6);
    const int lane = threadIdx.x & 63;
    const int b = wave >> 12;        // wave / T  (B*T/T = 64 values)
    const int t = wave & (T - 1);

    const float4 xv = *(const float4*)(x_ws + (size_t)b * D + lane * 4);
    const float4 sv = *(const float4*)(src + (size_t)t * (B * D) + (size_t)b * D + lane * 4);

    float acc = xv.x * sv.x + xv.y * sv.y + xv.z * sv.z + xv.w * sv.w;
    for (int off = 32; off > 0; off >>= 1)
        acc += __shfl_down(acc, off, 64);

    if (lane == 0) out[(size_t)b * T + t] = acc * 0.0625f;  // 1/sqrt(256)
}

extern "C" void kernel_launch(void* const* d_in, const int* in_sizes, int n_in,
                              void* d_out, int out_size, void* d_ws, size_t ws_size,
                              hipStream_t stream) {
    const int*   batch_nodes = (const int*)d_in[0];   // [B,T] int32
    const int*   exe         = (const int*)d_in[1];   // [B,T] int32
    const float* src         = (const float*)d_in[2]; // [T,B,D] f32
    const float* graph_dict  = (const float*)d_in[3]; // [GNN_NODES,D] f32
    const float* W0          = (const float*)d_in[4]; // [D,D] f32
    const float* b0          = (const float*)d_in[5]; // [D] f32

    float* out    = (float*)d_out;        // [B*T] sim, then [B] gate
    float* gate   = out + (size_t)B * T;
    float* x_ws   = (float*)d_ws;         // B*D floats = 64 KB

    prep_kernel<<<B, 256, 0, stream>>>(batch_nodes, exe, graph_dict, W0, b0, x_ws, gate);
    sim_kernel<<<(B * T) / 4, 256, 0, stream>>>(src, x_ws, out);
}

// Round 2
// 410.480 us; speedup vs baseline: 1.0051x; 1.0051x over previous
//
#include <hip/hip_runtime.h>

#define T 4096
#define B 64
#define D 256

// Kernel A: per-batch doc search + gather + linear0 (x = g @ W0^T + b0), gate.
// 64 blocks x 256 threads. Tiny (~1MB exe scan + 64KB W0 per block from L2).
__global__ __launch_bounds__(256) void prep_kernel(
    const int* __restrict__ batch_nodes, const int* __restrict__ exe,
    const float* __restrict__ graph_dict, const float* __restrict__ W0,
    const float* __restrict__ b0, float* __restrict__ x_ws,
    float* __restrict__ gate_out)
{
    const int b   = blockIdx.x;
    const int tid = threadIdx.x;

    // last t with exe[b,t]==1 (thread-strided; t ascending so overwrite = max)
    int best = -1;
    const int* erow = exe + (size_t)b * T;
    for (int t = tid; t < T; t += 256)
        if (erow[t] == 1) best = t;

    for (int off = 32; off > 0; off >>= 1) {
        int o = __shfl_down(best, off, 64);
        best = best > o ? best : o;
    }
    __shared__ int sred[4];
    __shared__ int s_doc;
    const int wid = tid >> 6, lane = tid & 63;
    if (lane == 0) sred[wid] = best;
    __syncthreads();
    if (tid == 0) {
        int m = sred[0];
        if (sred[1] > m) m = sred[1];
        if (sred[2] > m) m = sred[2];
        if (sred[3] > m) m = sred[3];
        s_doc = m;
    }
    __syncthreads();

    const int  doc  = s_doc;
    const bool has  = doc >= 0;
    const int  safe = has ? doc : 0;
    const int  node = batch_nodes[(size_t)b * T + safe];

    __shared__ float s_g[D];
    s_g[tid] = has ? graph_dict[(size_t)node * D + tid] : 0.0f;
    __syncthreads();

    // x[b,e] = b0[e] + sum_d g[d] * W0[e,d]   (when !has: x = b0 — bias stays!)
    const int e = tid;
    const float4* wrow = (const float4*)(W0 + (size_t)e * D);
    float acc = b0[e];
    #pragma unroll 8
    for (int d4 = 0; d4 < D / 4; ++d4) {
        float4 w = wrow[d4];
        acc += s_g[d4 * 4 + 0] * w.x + s_g[d4 * 4 + 1] * w.y
             + s_g[d4 * 4 + 2] * w.z + s_g[d4 * 4 + 3] * w.w;
    }
    x_ws[(size_t)b * D + e] = acc;
    if (tid == 0) gate_out[b] = has ? 1.0f : 0.0f;
}

// Kernel B v2: one block per t (4096 blocks). Block reads the contiguous
// 64 KB src[t,:,:] slab. Wave w owns b = w*16 .. w*16+15; the 16-iteration
// loop is fully unrolled -> 32 independent float4 loads in flight per wave
// (16 src from HBM, 16 x from L1/L2 — x_ws is only 64 KB total).
// No LDS -> occupancy limited by VGPRs only.
__global__ __launch_bounds__(256) void sim_kernel(
    const float* __restrict__ src, const float* __restrict__ x_ws,
    float* __restrict__ out)
{
    const int t    = blockIdx.x;
    const int wave = threadIdx.x >> 6;
    const int lane = threadIdx.x & 63;
    const int b0   = wave * 16;

    const float* srow = src  + (size_t)t * (B * D) + (size_t)b0 * D + lane * 4;
    const float* xrow = x_ws + (size_t)b0 * D + lane * 4;

    float res = 0.0f;
    #pragma unroll
    for (int i = 0; i < 16; ++i) {
        const float4 sv = *(const float4*)(srow + i * D);
        const float4 xv = *(const float4*)(xrow + i * D);
        float a = sv.x * xv.x + sv.y * xv.y + sv.z * xv.z + sv.w * xv.w;
        a += __shfl_xor(a, 1, 64);
        a += __shfl_xor(a, 2, 64);
        a += __shfl_xor(a, 4, 64);
        a += __shfl_xor(a, 8, 64);
        a += __shfl_xor(a, 16, 64);
        a += __shfl_xor(a, 32, 64);
        if (lane == i) res = a;     // lane i keeps b0+i's result
    }
    if (lane < 16)
        out[(size_t)(b0 + lane) * T + t] = res * 0.0625f;  // 1/sqrt(256)
}

extern "C" void kernel_launch(void* const* d_in, const int* in_sizes, int n_in,
                              void* d_out, int out_size, void* d_ws, size_t ws_size,
                              hipStream_t stream) {
    const int*   batch_nodes = (const int*)d_in[0];   // [B,T] int32
    const int*   exe         = (const int*)d_in[1];   // [B,T] int32
    const float* src         = (const float*)d_in[2]; // [T,B,D] f32
    const float* graph_dict  = (const float*)d_in[3]; // [GNN_NODES,D] f32
    const float* W0          = (const float*)d_in[4]; // [D,D] f32
    const float* b0          = (const float*)d_in[5]; // [D] f32

    float* out  = (float*)d_out;          // [B*T] sim, then [B] gate
    float* gate = out + (size_t)B * T;
    float* x_ws = (float*)d_ws;           // B*D floats = 64 KB

    prep_kernel<<<B, 256, 0, stream>>>(batch_nodes, exe, graph_dict, W0, b0, x_ws, gate);
    sim_kernel<<<T, 256, 0, stream>>>(src, x_ws, out);
}